// Round 7
// baseline (198.278 us; speedup 1.0000x reference)
//
#include <hip/hip_runtime.h>
#include <math.h>

static constexpr int Dh = 128;
static constexpr int NH = 4;
static constexpr int NB = 16;
static constexpr int SS = 1024;
static constexpr float NEGF = -1e9f;
static constexpr float SCALE = 0.08838834764831843f;  // 1/sqrt(128)
static constexpr float LOG2E = 1.4426950408889634f;

typedef short s16x8 __attribute__((ext_vector_type(8)));
typedef short s16x4 __attribute__((ext_vector_type(4)));
typedef float f32x4 __attribute__((ext_vector_type(4)));

#define MFMA32(a, b, c) __builtin_amdgcn_mfma_f32_16x16x32_bf16(a, b, c, 0, 0, 0)
// K=16 bf16 MFMA: layouts HW-validated (byte-identical absmax across rounds).
#define MFMA16(a, b, c) __builtin_amdgcn_mfma_f32_16x16x16bf16_1k(a, b, c, 0, 0, 0)

__device__ inline ushort f2bf(float f) {
    union { float f; unsigned u; } v; v.f = f;
    unsigned r = v.u + 0x7FFFu + ((v.u >> 16) & 1u);
    return (ushort)(r >> 16);
}

// ---------------- K0: LN partial sums + bit-mask prep + weight bf16 pre-convert ----------------
__global__ __launch_bounds__(256) void ln_mask_kernel(const float* __restrict__ x,
                                                      float* __restrict__ part,
                                                      const int* __restrict__ edge,
                                                      unsigned long long* __restrict__ mbit,
                                                      const float* __restrict__ w_in,
                                                      const float* __restrict__ w_out,
                                                      ushort* __restrict__ wb,
                                                      ushort* __restrict__ wob) {
    const int b = blockIdx.x >> 4, p = blockIdx.x & 15;
    const int tid = threadIdx.x;
    const float4* xb4 = (const float4*)(x + (size_t)b * SS * Dh) + p * 2048;
    float s = 0.f, ss = 0.f;
    for (int i = tid; i < 2048; i += 256) {
        float4 v = xb4[i];
        s  += v.x + v.y + v.z + v.w;
        ss += v.x * v.x + v.y * v.y + v.z * v.z + v.w * v.w;
    }
    __shared__ float r1[256], r2[256];
    r1[tid] = s; r2[tid] = ss;
    __syncthreads();
    for (int off = 128; off > 0; off >>= 1) {
        if (tid < off) { r1[tid] += r1[tid + off]; r2[tid] += r2[tid + off]; }
        __syncthreads();
    }
    if (tid == 0) { part[blockIdx.x * 2] = r1[0]; part[blockIdx.x * 2 + 1] = r2[0]; }

    if (blockIdx.x < 64) {
        const int idx = blockIdx.x * 256 + tid;   // < 1024*16
        const int sr = idx >> 4, w = idx & 15;
        const int4* ep = (const int4*)(edge + (size_t)sr * SS + w * 64);
        unsigned long long m0 = 0, m1 = 0, m2 = 0, m3 = 0;
        #pragma unroll
        for (int j = 0; j < 16; ++j) {
            int4 e = ep[j];
            const int base = j * 4;
            m0 |= (e.x == 1) ? (1ull << (base + 0)) : 0ull;
            m1 |= (e.x == 2) ? (1ull << (base + 0)) : 0ull;
            m2 |= (e.x == 3) ? (1ull << (base + 0)) : 0ull;
            m3 |= (e.x == 4) ? (1ull << (base + 0)) : 0ull;
            m0 |= (e.y == 1) ? (1ull << (base + 1)) : 0ull;
            m1 |= (e.y == 2) ? (1ull << (base + 1)) : 0ull;
            m2 |= (e.y == 3) ? (1ull << (base + 1)) : 0ull;
            m3 |= (e.y == 4) ? (1ull << (base + 1)) : 0ull;
            m0 |= (e.z == 1) ? (1ull << (base + 2)) : 0ull;
            m1 |= (e.z == 2) ? (1ull << (base + 2)) : 0ull;
            m2 |= (e.z == 3) ? (1ull << (base + 2)) : 0ull;
            m3 |= (e.z == 4) ? (1ull << (base + 2)) : 0ull;
            m0 |= (e.w == 1) ? (1ull << (base + 3)) : 0ull;
            m1 |= (e.w == 2) ? (1ull << (base + 3)) : 0ull;
            m2 |= (e.w == 3) ? (1ull << (base + 3)) : 0ull;
            m3 |= (e.w == 4) ? (1ull << (base + 3)) : 0ull;
        }
        mbit[((size_t)0 * SS + sr) * 16 + w] = m0;
        mbit[((size_t)1 * SS + sr) * 16 + w] = m1;
        mbit[((size_t)2 * SS + sr) * 16 + w] = m2;
        mbit[((size_t)3 * SS + sr) * 16 + w] = m3;
    } else if (blockIdx.x < 160) {
        // W_in -> bf16 : 1536*128 elems; 96 blocks x 256 threads x 8
        const int slot = (blockIdx.x - 64) * 256 + tid;
        const float4* sp = (const float4*)w_in + (size_t)slot * 2;
        float4 a = sp[0], c = sp[1];
        s16x8 pk;
        pk[0] = (short)f2bf(a.x); pk[1] = (short)f2bf(a.y);
        pk[2] = (short)f2bf(a.z); pk[3] = (short)f2bf(a.w);
        pk[4] = (short)f2bf(c.x); pk[5] = (short)f2bf(c.y);
        pk[6] = (short)f2bf(c.z); pk[7] = (short)f2bf(c.w);
        *(s16x8*)(wb + (size_t)slot * 8) = pk;
    } else if (blockIdx.x < 192) {
        // W_out -> bf16 : 4*128*128 elems; 32 blocks x 256 threads x 8
        const int slot = (blockIdx.x - 160) * 256 + tid;
        const float4* sp = (const float4*)w_out + (size_t)slot * 2;
        float4 a = sp[0], c = sp[1];
        s16x8 pk;
        pk[0] = (short)f2bf(a.x); pk[1] = (short)f2bf(a.y);
        pk[2] = (short)f2bf(a.z); pk[3] = (short)f2bf(a.w);
        pk[4] = (short)f2bf(c.x); pk[5] = (short)f2bf(c.y);
        pk[6] = (short)f2bf(c.z); pk[7] = (short)f2bf(c.w);
        *(s16x8*)(wob + (size_t)slot * 8) = pk;
    }
}

// ---------------- K0.5: xn = LN(x) -> bf16 ----------------
__global__ __launch_bounds__(256) void xcast_kernel(const float* __restrict__ x,
                                                    const float* __restrict__ part,
                                                    ushort* __restrict__ xb) {
    const int b = blockIdx.x >> 6;
    float s = 0.f, ss = 0.f;
    #pragma unroll
    for (int p = 0; p < 16; ++p) { s += part[(b * 16 + p) * 2]; ss += part[(b * 16 + p) * 2 + 1]; }
    const float invN = 1.0f / (float)(SS * Dh);
    const float mu = s * invN;
    const float rstd = 1.0f / sqrtf(ss * invN - mu * mu + 1e-5f);
    const size_t base = ((size_t)blockIdx.x * 256 + threadIdx.x) * 8;
    float4 v0 = *(const float4*)(x + base);
    float4 v1 = *(const float4*)(x + base + 4);
    s16x8 pk;
    pk[0] = (short)f2bf((v0.x - mu) * rstd); pk[1] = (short)f2bf((v0.y - mu) * rstd);
    pk[2] = (short)f2bf((v0.z - mu) * rstd); pk[3] = (short)f2bf((v0.w - mu) * rstd);
    pk[4] = (short)f2bf((v1.x - mu) * rstd); pk[5] = (short)f2bf((v1.y - mu) * rstd);
    pk[6] = (short)f2bf((v1.z - mu) * rstd); pk[7] = (short)f2bf((v1.w - mu) * rstd);
    *(s16x8*)(xb + base) = pk;
}

// ---------------- K1: QKV projection, pure-bf16 MFMA ----------------
__global__ __launch_bounds__(256) void qkv_mfma_kernel(const ushort* __restrict__ xb,   // [16384][128] bf16 LN'd
                                                       const ushort* __restrict__ wb,   // [1536][128] bf16
                                                       const float* __restrict__ bias,  // [1536]
                                                       ushort* __restrict__ qo,
                                                       ushort* __restrict__ ko,
                                                       ushort* __restrict__ vto) {
    __shared__ ushort smem[2 * 128 * 72];     // As/Bs; epilogue alias Rs[128][136]
    ushort* As = smem;
    ushort* Bs = smem + 128 * 72;
    ushort* Rs = smem;
    const int tid = threadIdx.x, wave = tid >> 6, lane = tid & 63;
    const int lrow = lane & 15, quad = lane >> 4;
    const int wm = wave & 1, wn = wave >> 1;
    const int col0 = blockIdx.x * 128;
    const int row0 = blockIdx.y * 128;
    const int bb = row0 >> 10;

    f32x4 acc[4][4];
    #pragma unroll
    for (int mi = 0; mi < 4; ++mi)
        #pragma unroll
        for (int ni = 0; ni < 4; ++ni) acc[mi][ni] = (f32x4){0.f, 0.f, 0.f, 0.f};

    for (int kk = 0; kk < 128; kk += 64) {
        if (kk) __syncthreads();
        #pragma unroll
        for (int p = 0; p < 4; ++p) {
            int slot = p * 256 + tid;               // 1024 slots of 8 bf16
            int r = slot >> 3, c8 = (slot & 7) * 8;
            *(s16x8*)&As[r * 72 + c8] = *(const s16x8*)(xb + (size_t)(row0 + r) * Dh + kk + c8);
            *(s16x8*)&Bs[r * 72 + c8] = *(const s16x8*)(wb + (size_t)(col0 + r) * Dh + kk + c8);
        }
        __syncthreads();
        #pragma unroll
        for (int kc = 0; kc < 2; ++kc) {
            s16x8 af[4], bf[4];
            #pragma unroll
            for (int mi = 0; mi < 4; ++mi)
                af[mi] = *(const s16x8*)&As[(wm * 64 + 16 * mi + lrow) * 72 + kc * 32 + quad * 8];
            #pragma unroll
            for (int ni = 0; ni < 4; ++ni)
                bf[ni] = *(const s16x8*)&Bs[(wn * 64 + 16 * ni + lrow) * 72 + kc * 32 + quad * 8];
            #pragma unroll
            for (int mi = 0; mi < 4; ++mi)
                #pragma unroll
                for (int ni = 0; ni < 4; ++ni)
                    acc[mi][ni] = MFMA32(af[mi], bf[ni], acc[mi][ni]);
        }
    }

    const int seg = col0 % 384, typ = seg >> 7, h = col0 / 384;
    const size_t bh = (size_t)bb * NH + h;
    const int sl_blk = row0 & 1023;
    float bia[4];
    #pragma unroll
    for (int ni = 0; ni < 4; ++ni) bia[ni] = bias[col0 + wn * 64 + 16 * ni + lrow];
    // Q scaled by 1/sqrt(D) * log2(e): attention softmax runs in exp2 domain.
    const float sc = (typ == 0) ? SCALE * LOG2E : 1.f;

    __syncthreads();
    if (typ < 2) {
        #pragma unroll
        for (int mi = 0; mi < 4; ++mi)
            #pragma unroll
            for (int ni = 0; ni < 4; ++ni)
                #pragma unroll
                for (int reg = 0; reg < 4; ++reg)
                    Rs[(wm * 64 + 16 * mi + quad * 4 + reg) * 136 + wn * 64 + 16 * ni + lrow]
                        = f2bf((acc[mi][ni][reg] + bia[ni]) * sc);
    } else {
        #pragma unroll
        for (int mi = 0; mi < 4; ++mi)
            #pragma unroll
            for (int ni = 0; ni < 4; ++ni) {
                ushort4 pk;
                pk.x = f2bf(acc[mi][ni][0] + bia[ni]);
                pk.y = f2bf(acc[mi][ni][1] + bia[ni]);
                pk.z = f2bf(acc[mi][ni][2] + bia[ni]);
                pk.w = f2bf(acc[mi][ni][3] + bia[ni]);
                *(ushort4*)&Rs[(wn * 64 + 16 * ni + lrow) * 136 + wm * 64 + 16 * mi + quad * 4] = pk;
            }
    }
    __syncthreads();

    ushort* dstb;
    int pitch;
    if (typ == 0)      { dstb = qo  + bh * SS * 128 + (size_t)sl_blk * 128; pitch = 128; }
    else if (typ == 1) { dstb = ko  + bh * SS * 128 + (size_t)sl_blk * 128; pitch = 128; }
    else               { dstb = vto + bh * (size_t)128 * SS + sl_blk;       pitch = SS;  }
    #pragma unroll
    for (int p = 0; p < 8; ++p) {
        int slot = p * 256 + tid;
        int r = slot >> 4, c8 = (slot & 15) * 8;
        *(s16x8*)&dstb[(size_t)r * pitch + c8] = *(const s16x8*)&Rs[r * 136 + c8];
    }
}

// ---------------- K2: barrier-free flash attention.
// Block = 64 q-rows x full keys: 4 waves = 2 q-groups x 2 key-halves. Each wave scans its
// 512-key half in 16 x 32-key tiles staged into a PRIVATE 16KB LDS region (XOR-swizzled,
// layouts proven in r4/r5) -- ds_write->ds_read within one wave: NO __syncthreads in the loop.
// One 2-way flash merge at the end; all 4 waves split the out-projection.
// All register-array indices compile-time literal (rule #20). ----------------
__global__ __launch_bounds__(256, 2) void attn_fused_kernel(const ushort* __restrict__ qg_,
                                                            const ushort* __restrict__ kg_,
                                                            const ushort* __restrict__ vg_,
                                                            const unsigned long long* __restrict__ mbit,
                                                            const ushort* __restrict__ wob,   // [4][128][128] bf16
                                                            const float* __restrict__ bo,
                                                            float* __restrict__ out) {
    // grid (64, 16): blockIdx.x = (b,h) -> id%8 pins all 16 q-tiles of a (b,h) to one XCD L2
    const int bhi = blockIdx.x, qt = blockIdx.y;
    const int b = bhi >> 2, h = bhi & 3;
    const int tid = threadIdx.x;
    const int wave = tid >> 6, lane = tid & 63;
    const int qgrp = wave & 1;        // q-row group (32 rows)
    const int kh = wave >> 1;         // key half (0: keys 0-511, 1: 512-1023)
    const int lrow = lane & 15, quad = lane >> 4;
    const int s0 = qt * 64 + qgrp * 32;

    __shared__ ushort smem[32768];    // 4 waves x (Ks 32x128 + Vt 128x32) = 64 KB
    ushort* Ks = smem + wave * 8192;  // [32 key][128 d], XOR-swizzled (c ^ ((r&7)<<3))
    ushort* Vt = Ks + 4096;           // [128 d][32 key], XOR-swizzled (c ^ ((r&3)<<3))

    const size_t bh = (size_t)(b * NH + h);
    const ushort* qg = qg_ + bh * SS * 128;
    const ushort* kg = kg_ + bh * SS * 128 + (size_t)(kh * 512) * 128;
    const ushort* vg = vg_ + bh * (size_t)128 * SS + kh * 512;
    const unsigned long long* mrow0 = mbit + ((size_t)h * SS + (s0 + lrow)) * 16 + kh * 8;
    const unsigned long long* mrow1 = mrow0 + 16 * 16;

    // Q fragments (B-operand of S^T MFMA32): n=q=lane&15, k=kc*32+quad*8+j
    s16x8 qf[2][4];
    #pragma unroll
    for (int g = 0; g < 2; ++g) {
        const ushort* qr = qg + (size_t)(s0 + 16 * g + lrow) * 128 + quad * 8;
        #pragma unroll
        for (int kc = 0; kc < 4; ++kc) qf[g][kc] = *(const s16x8*)(qr + kc * 32);
    }

    // per-lane staging coords: K 32x128 (512 x 8-elem chunks), V 128x32
    const int kc8 = (lane & 15) * 8, krb = lane >> 4;   // K row = p*4 + krb
    const int vc8 = (lane & 3) * 8,  vrb = lane >> 2;   // V row = p*16 + vrb

    // prologue: load tile 0 of this key-half
    s16x8 kreg[8], vreg[8];
    #pragma unroll
    for (int p = 0; p < 8; ++p)
        kreg[p] = *(const s16x8*)(kg + (size_t)(p * 4 + krb) * 128 + kc8);
    #pragma unroll
    for (int p = 0; p < 8; ++p)
        vreg[p] = *(const s16x8*)(vg + (size_t)(p * 16 + vrb) * SS + vc8);

    // O^T accumulators: D[m=d][n=q]: q = lane&15, d = 16*nb+quad*4+reg
    f32x4 oacc[2][8];
    #pragma unroll
    for (int g = 0; g < 2; ++g)
        #pragma unroll
        for (int nb = 0; nb < 8; ++nb) oacc[g][nb] = (f32x4){0.f, 0.f, 0.f, 0.f};
    float m_run[2] = {-INFINITY, -INFINITY};
    float l_run[2] = {0.f, 0.f};

    for (int i = 0; i < 16; ++i) {
        // ---- stage tile i into private buffer (no barrier: own region, own wave) ----
        #pragma unroll
        for (int p = 0; p < 8; ++p) {
            const int r = p * 4 + krb;
            *(s16x8*)&Ks[r * 128 + (kc8 ^ ((r & 7) << 3))] = kreg[p];
        }
        #pragma unroll
        for (int p = 0; p < 8; ++p) {
            const int r = p * 16 + vrb;
            *(s16x8*)&Vt[r * 32 + (vc8 ^ ((r & 3) << 3))] = vreg[p];
        }
        // issue next-tile global loads (latency hidden under this tile's compute)
        if (i < 15) {
            const int t1 = (i + 1) * 32;
            #pragma unroll
            for (int p = 0; p < 8; ++p)
                kreg[p] = *(const s16x8*)(kg + (size_t)(t1 + p * 4 + krb) * 128 + kc8);
            #pragma unroll
            for (int p = 0; p < 8; ++p)
                vreg[p] = *(const s16x8*)(vg + (size_t)(p * 16 + vrb) * SS + t1 + vc8);
        }

        const unsigned mw0 = (unsigned)(mrow0[i >> 1] >> ((i & 1) * 32));
        const unsigned mw1 = (unsigned)(mrow1[i >> 1] >> ((i & 1) * 32));

        // ---- S^T = K Q'^T : D[m=key][n=q]; key = 16*cb+quad*4+reg, q = lane&15 ----
        f32x4 sacc[2][2];
        sacc[0][0] = (f32x4){0.f, 0.f, 0.f, 0.f}; sacc[0][1] = (f32x4){0.f, 0.f, 0.f, 0.f};
        sacc[1][0] = (f32x4){0.f, 0.f, 0.f, 0.f}; sacc[1][1] = (f32x4){0.f, 0.f, 0.f, 0.f};
        #pragma unroll
        for (int cb = 0; cb < 2; ++cb) {
            s16x8 kf[4];
            const int krow = 16 * cb + lrow;
            #pragma unroll
            for (int kc = 0; kc < 4; ++kc)
                kf[kc] = *(const s16x8*)&Ks[krow * 128 + ((kc * 32 + quad * 8) ^ ((lrow & 7) << 3))];
            #pragma unroll
            for (int kc = 0; kc < 4; ++kc) {
                sacc[0][cb] = MFMA32(kf[kc], qf[0][kc], sacc[0][cb]);
                sacc[1][cb] = MFMA32(kf[kc], qf[1][kc], sacc[1][cb]);
            }
        }

        // ---- softmax (per-lane state, q=lane&15), exp2 domain + deferred-max rescale ----
        s16x4 pf[2][2];
        #pragma unroll
        for (int g = 0; g < 2; ++g) {
            const unsigned mw = g ? mw1 : mw0;
            float sv[2][4];
            float tm = -INFINITY;
            #pragma unroll
            for (int cb = 0; cb < 2; ++cb) {
                unsigned nib = (mw >> (16 * cb + quad * 4)) & 0xFu;
                #pragma unroll
                for (int r = 0; r < 4; ++r) {
                    sv[cb][r] = (nib & (1u << r)) ? sacc[g][cb][r] : NEGF;
                    tm = fmaxf(tm, sv[cb][r]);
                }
            }
            tm = fmaxf(tm, __shfl_xor(tm, 16));
            tm = fmaxf(tm, __shfl_xor(tm, 32));
            float mn = m_run[g];
            // deferred-max (T13): skip O/l rescale while max grows < 12 log2-units (~e^8.3)
            if (!__all(tm <= mn + 12.f)) {
                mn = fmaxf(mn, tm);
                float al = __builtin_amdgcn_exp2f(m_run[g] - mn);
                l_run[g] *= al;
                #pragma unroll
                for (int nb = 0; nb < 8; ++nb)
                    #pragma unroll
                    for (int r = 0; r < 4; ++r) oacc[g][nb][r] *= al;
                m_run[g] = mn;
            }
            float rs = 0.f;
            #pragma unroll
            for (int cb = 0; cb < 2; ++cb) {
                float p0 = __builtin_amdgcn_exp2f(sv[cb][0] - mn);
                float p1 = __builtin_amdgcn_exp2f(sv[cb][1] - mn);
                float p2 = __builtin_amdgcn_exp2f(sv[cb][2] - mn);
                float p3 = __builtin_amdgcn_exp2f(sv[cb][3] - mn);
                rs += (p0 + p1) + (p2 + p3);
                s16x4 pk;
                pk[0] = (short)f2bf(p0); pk[1] = (short)f2bf(p1);
                pk[2] = (short)f2bf(p2); pk[3] = (short)f2bf(p3);
                pf[g][cb] = pk;
            }
            rs += __shfl_xor(rs, 16);
            rs += __shfl_xor(rs, 32);
            l_run[g] += rs;
        }

        // ---- O^T += V^T P^T : MFMA16, A = V^T frag (private LDS), B = pf (regs) ----
        #pragma unroll
        for (int nb = 0; nb < 8; ++nb) {
            const int vrow = 16 * nb + lrow;
            #pragma unroll
            for (int kb = 0; kb < 2; ++kb) {
                s16x4 vf = *(const s16x4*)&Vt[vrow * 32 + ((kb * 16 + quad * 4) ^ ((lrow & 3) << 3))];
                oacc[0][nb] = MFMA16(vf, pf[0][kb], oacc[0][nb]);
                oacc[1][nb] = MFMA16(vf, pf[1][kb], oacc[1][nb]);
            }
        }
    }

    // ---- 2-way split-K merge (exact flash combine). Arena stride 69 (5*lane%32: 2-way max).
    float* arena = (float*)smem;
    float* slot0 = arena + (size_t)qgrp * 4416 + lane * 69;
    ushort* aO = smem + 17664;   // [64 q][136] bf16 normalized O
    __syncthreads();             // all waves done with private buffers (arena aliases them)
    if (kh == 1) {               // key-half-1 waves publish both g states
        #pragma unroll
        for (int nb = 0; nb < 8; ++nb)
            #pragma unroll
            for (int r = 0; r < 4; ++r) {
                slot0[nb * 4 + r]      = oacc[0][nb][r];
                slot0[34 + nb * 4 + r] = oacc[1][nb][r];
            }
        slot0[32] = m_run[0]; slot0[33] = l_run[0];
        slot0[66] = m_run[1]; slot0[67] = l_run[1];
    }
    __syncthreads();
    if (kh == 0) {               // key-half-0 waves merge, normalize, write aO
        float mB0 = slot0[32], lB0 = slot0[33];
        float mB1 = slot0[66], lB1 = slot0[67];
        float mN0 = fmaxf(m_run[0], mB0);
        float aA0 = __builtin_amdgcn_exp2f(m_run[0] - mN0);
        float aB0 = __builtin_amdgcn_exp2f(mB0 - mN0);
        float mN1 = fmaxf(m_run[1], mB1);
        float aA1 = __builtin_amdgcn_exp2f(m_run[1] - mN1);
        float aB1 = __builtin_amdgcn_exp2f(mB1 - mN1);
        float inv0 = 1.0f / (l_run[0] * aA0 + lB0 * aB0);
        float inv1 = 1.0f / (l_run[1] * aA1 + lB1 * aB1);
        #pragma unroll
        for (int nb = 0; nb < 8; ++nb) {
            ushort4 p0, p1;
            p0.x = f2bf((oacc[0][nb][0] * aA0 + slot0[nb * 4 + 0] * aB0) * inv0);
            p0.y = f2bf((oacc[0][nb][1] * aA0 + slot0[nb * 4 + 1] * aB0) * inv0);
            p0.z = f2bf((oacc[0][nb][2] * aA0 + slot0[nb * 4 + 2] * aB0) * inv0);
            p0.w = f2bf((oacc[0][nb][3] * aA0 + slot0[nb * 4 + 3] * aB0) * inv0);
            p1.x = f2bf((oacc[1][nb][0] * aA1 + slot0[34 + nb * 4 + 0] * aB1) * inv1);
            p1.y = f2bf((oacc[1][nb][1] * aA1 + slot0[34 + nb * 4 + 1] * aB1) * inv1);
            p1.z = f2bf((oacc[1][nb][2] * aA1 + slot0[34 + nb * 4 + 2] * aB1) * inv1);
            p1.w = f2bf((oacc[1][nb][3] * aA1 + slot0[34 + nb * 4 + 3] * aB1) * inv1);
            *(ushort4*)&aO[(qgrp * 32 + lrow) * 136 + nb * 16 + quad * 4] = p0;
            *(ushort4*)&aO[(qgrp * 32 + 16 + lrow) * 136 + nb * 16 + quad * 4] = p1;
        }
    }
    __syncthreads();

    // ---- out-projection, all 4 waves: rows = own q-group, eb range = own kh half ----
    const ushort* wbh = wob + (size_t)h * Dh * Dh;
    const size_t orow0 = (size_t)b * SS + qt * 64 + qgrp * 32;
    #pragma unroll
    for (int e2 = 0; e2 < 4; ++e2) {
        const int eb = kh * 4 + e2;
        float bia = bo[h * Dh + eb * 16 + lrow];
        f32x4 facc0 = (f32x4){0.f, 0.f, 0.f, 0.f};
        f32x4 facc1 = (f32x4){0.f, 0.f, 0.f, 0.f};
        const ushort* wr = wbh + (size_t)(eb * 16 + lrow) * Dh + quad * 4;
        #pragma unroll
        for (int nb = 0; nb < 8; ++nb) {
            s16x4 a0 = *(const s16x4*)&aO[(qgrp * 32 + lrow) * 136 + nb * 16 + quad * 4];
            s16x4 a1 = *(const s16x4*)&aO[(qgrp * 32 + 16 + lrow) * 136 + nb * 16 + quad * 4];
            s16x4 wf = *(const s16x4*)(wr + nb * 16);   // B[k=d][n=e]
            facc0 = MFMA16(a0, wf, facc0);
            facc1 = MFMA16(a1, wf, facc1);
        }
        #pragma unroll
        for (int reg = 0; reg < 4; ++reg) {
            out[(orow0 + quad * 4 + reg) * (NH * Dh) + h * Dh + eb * 16 + lrow] = facc0[reg] + bia;
            out[(orow0 + 16 + quad * 4 + reg) * (NH * Dh) + h * Dh + eb * 16 + lrow] = facc1[reg] + bia;
        }
    }
}

extern "C" void kernel_launch(void* const* d_in, const int* in_sizes, int n_in,
                              void* d_out, int out_size, void* d_ws, size_t ws_size,
                              hipStream_t stream) {
    const float* x     = (const float*)d_in[0];
    const int*   edge  = (const int*)d_in[1];
    const float* w_in  = (const float*)d_in[2];
    const float* b_in  = (const float*)d_in[3];
    const float* w_out = (const float*)d_in[4];
    const float* b_out = (const float*)d_in[5];
    float* out = (float*)d_out;

    float* ws   = (float*)d_ws;
    float* part = ws;                                              // 512 floats (reserve 1024)
    unsigned long long* mbit = (unsigned long long*)(ws + 1024);   // [4][1024][16] u64 = 512 KB
    ushort* qo  = (ushort*)(mbit + (size_t)NH * SS * 16);
    const size_t QSZ = (size_t)NB * NH * SS * 128;
    ushort* ko  = qo + QSZ;
    ushort* vto = ko + QSZ;                                        // [b][h][128][s]
    ushort* xb  = vto + QSZ;                                       // [16384][128] bf16 LN'd x (4 MB)
    ushort* wb  = xb + (size_t)NB * SS * Dh;                       // [1536][128] bf16 W_in
    ushort* wob = wb + (size_t)NH * 3 * Dh * Dh;                   // [4][128][128] bf16 W_out

    ln_mask_kernel<<<256, 256, 0, stream>>>(x, part, edge, mbit, w_in, w_out, wb, wob);
    xcast_kernel<<<1024, 256, 0, stream>>>(x, part, xb);
    qkv_mfma_kernel<<<dim3(12, 128), 256, 0, stream>>>(xb, wb, b_in, qo, ko, vto);
    attn_fused_kernel<<<dim3(NB * NH, SS / 64), 256, 0, stream>>>(qo, ko, vto, mbit, wob, b_out, out);
}

// Round 8
// 164.864 us; speedup vs baseline: 1.2027x; 1.2027x over previous
//
#include <hip/hip_runtime.h>
#include <math.h>

static constexpr int Dh = 128;
static constexpr int NH = 4;
static constexpr int NB = 16;
static constexpr int SS = 1024;
static constexpr float NEGF = -1e9f;
static constexpr float SCALE = 0.08838834764831843f;  // 1/sqrt(128)

typedef short s16x8 __attribute__((ext_vector_type(8)));
typedef short s16x4 __attribute__((ext_vector_type(4)));
typedef float f32x4 __attribute__((ext_vector_type(4)));

#define MFMA32(a, b, c) __builtin_amdgcn_mfma_f32_16x16x32_bf16(a, b, c, 0, 0, 0)
// K=16 bf16 MFMA: layouts HW-validated (byte-identical absmax across rounds).
#define MFMA16(a, b, c) __builtin_amdgcn_mfma_f32_16x16x16bf16_1k(a, b, c, 0, 0, 0)

__device__ inline ushort f2bf(float f) {
    union { float f; unsigned u; } v; v.f = f;
    unsigned r = v.u + 0x7FFFu + ((v.u >> 16) & 1u);
    return (ushort)(r >> 16);
}

// ---------------- K0: LN partial sums + bit-mask prep + W_in bf16 pre-convert ----------------
__global__ __launch_bounds__(256) void ln_mask_kernel(const float* __restrict__ x,
                                                      float* __restrict__ part,
                                                      const int* __restrict__ edge,
                                                      unsigned long long* __restrict__ mbit,
                                                      const float* __restrict__ w_in,
                                                      ushort* __restrict__ wb) {
    const int b = blockIdx.x >> 4, p = blockIdx.x & 15;
    const int tid = threadIdx.x;
    const float4* xb4 = (const float4*)(x + (size_t)b * SS * Dh) + p * 2048;
    float s = 0.f, ss = 0.f;
    for (int i = tid; i < 2048; i += 256) {
        float4 v = xb4[i];
        s  += v.x + v.y + v.z + v.w;
        ss += v.x * v.x + v.y * v.y + v.z * v.z + v.w * v.w;
    }
    __shared__ float r1[256], r2[256];
    r1[tid] = s; r2[tid] = ss;
    __syncthreads();
    for (int off = 128; off > 0; off >>= 1) {
        if (tid < off) { r1[tid] += r1[tid + off]; r2[tid] += r2[tid + off]; }
        __syncthreads();
    }
    if (tid == 0) { part[blockIdx.x * 2] = r1[0]; part[blockIdx.x * 2 + 1] = r2[0]; }

    if (blockIdx.x < 64) {
        const int idx = blockIdx.x * 256 + tid;   // < 1024*16
        const int sr = idx >> 4, w = idx & 15;
        const int4* ep = (const int4*)(edge + (size_t)sr * SS + w * 64);
        unsigned long long m0 = 0, m1 = 0, m2 = 0, m3 = 0;
        #pragma unroll
        for (int j = 0; j < 16; ++j) {
            int4 e = ep[j];
            const int base = j * 4;
            m0 |= (e.x == 1) ? (1ull << (base + 0)) : 0ull;
            m1 |= (e.x == 2) ? (1ull << (base + 0)) : 0ull;
            m2 |= (e.x == 3) ? (1ull << (base + 0)) : 0ull;
            m3 |= (e.x == 4) ? (1ull << (base + 0)) : 0ull;
            m0 |= (e.y == 1) ? (1ull << (base + 1)) : 0ull;
            m1 |= (e.y == 2) ? (1ull << (base + 1)) : 0ull;
            m2 |= (e.y == 3) ? (1ull << (base + 1)) : 0ull;
            m3 |= (e.y == 4) ? (1ull << (base + 1)) : 0ull;
            m0 |= (e.z == 1) ? (1ull << (base + 2)) : 0ull;
            m1 |= (e.z == 2) ? (1ull << (base + 2)) : 0ull;
            m2 |= (e.z == 3) ? (1ull << (base + 2)) : 0ull;
            m3 |= (e.z == 4) ? (1ull << (base + 2)) : 0ull;
            m0 |= (e.w == 1) ? (1ull << (base + 3)) : 0ull;
            m1 |= (e.w == 2) ? (1ull << (base + 3)) : 0ull;
            m2 |= (e.w == 3) ? (1ull << (base + 3)) : 0ull;
            m3 |= (e.w == 4) ? (1ull << (base + 3)) : 0ull;
        }
        mbit[((size_t)0 * SS + sr) * 16 + w] = m0;
        mbit[((size_t)1 * SS + sr) * 16 + w] = m1;
        mbit[((size_t)2 * SS + sr) * 16 + w] = m2;
        mbit[((size_t)3 * SS + sr) * 16 + w] = m3;
    } else if (blockIdx.x < 160) {
        // W_in -> bf16 : 1536*128 elems; 96 blocks x 256 threads x 8
        const int slot = (blockIdx.x - 64) * 256 + tid;
        const float4* sp = (const float4*)w_in + (size_t)slot * 2;
        float4 a = sp[0], c = sp[1];
        s16x8 pk;
        pk[0] = (short)f2bf(a.x); pk[1] = (short)f2bf(a.y);
        pk[2] = (short)f2bf(a.z); pk[3] = (short)f2bf(a.w);
        pk[4] = (short)f2bf(c.x); pk[5] = (short)f2bf(c.y);
        pk[6] = (short)f2bf(c.z); pk[7] = (short)f2bf(c.w);
        *(s16x8*)(wb + (size_t)slot * 8) = pk;
    }
}

// ---------------- K0.5: xn = LN(x) -> bf16 ----------------
__global__ __launch_bounds__(256) void xcast_kernel(const float* __restrict__ x,
                                                    const float* __restrict__ part,
                                                    ushort* __restrict__ xb) {
    const int b = blockIdx.x >> 6;
    float s = 0.f, ss = 0.f;
    #pragma unroll
    for (int p = 0; p < 16; ++p) { s += part[(b * 16 + p) * 2]; ss += part[(b * 16 + p) * 2 + 1]; }
    const float invN = 1.0f / (float)(SS * Dh);
    const float mu = s * invN;
    const float rstd = 1.0f / sqrtf(ss * invN - mu * mu + 1e-5f);
    const size_t base = ((size_t)blockIdx.x * 256 + threadIdx.x) * 8;
    float4 v0 = *(const float4*)(x + base);
    float4 v1 = *(const float4*)(x + base + 4);
    s16x8 pk;
    pk[0] = (short)f2bf((v0.x - mu) * rstd); pk[1] = (short)f2bf((v0.y - mu) * rstd);
    pk[2] = (short)f2bf((v0.z - mu) * rstd); pk[3] = (short)f2bf((v0.w - mu) * rstd);
    pk[4] = (short)f2bf((v1.x - mu) * rstd); pk[5] = (short)f2bf((v1.y - mu) * rstd);
    pk[6] = (short)f2bf((v1.z - mu) * rstd); pk[7] = (short)f2bf((v1.w - mu) * rstd);
    *(s16x8*)(xb + base) = pk;
}

// ---------------- K1: QKV projection, pure-bf16 MFMA (sc = SCALE; attn uses __expf) ----------------
__global__ __launch_bounds__(256) void qkv_mfma_kernel(const ushort* __restrict__ xb,   // [16384][128] bf16 LN'd
                                                       const ushort* __restrict__ wb,   // [1536][128] bf16
                                                       const float* __restrict__ bias,  // [1536]
                                                       ushort* __restrict__ qo,
                                                       ushort* __restrict__ ko,
                                                       ushort* __restrict__ vto) {
    __shared__ ushort smem[2 * 128 * 72];     // As/Bs; epilogue alias Rs[128][136]
    ushort* As = smem;
    ushort* Bs = smem + 128 * 72;
    ushort* Rs = smem;
    const int tid = threadIdx.x, wave = tid >> 6, lane = tid & 63;
    const int lrow = lane & 15, quad = lane >> 4;
    const int wm = wave & 1, wn = wave >> 1;
    const int col0 = blockIdx.x * 128;
    const int row0 = blockIdx.y * 128;
    const int bb = row0 >> 10;

    f32x4 acc[4][4];
    #pragma unroll
    for (int mi = 0; mi < 4; ++mi)
        #pragma unroll
        for (int ni = 0; ni < 4; ++ni) acc[mi][ni] = (f32x4){0.f, 0.f, 0.f, 0.f};

    for (int kk = 0; kk < 128; kk += 64) {
        if (kk) __syncthreads();
        #pragma unroll
        for (int p = 0; p < 4; ++p) {
            int slot = p * 256 + tid;               // 1024 slots of 8 bf16
            int r = slot >> 3, c8 = (slot & 7) * 8;
            *(s16x8*)&As[r * 72 + c8] = *(const s16x8*)(xb + (size_t)(row0 + r) * Dh + kk + c8);
            *(s16x8*)&Bs[r * 72 + c8] = *(const s16x8*)(wb + (size_t)(col0 + r) * Dh + kk + c8);
        }
        __syncthreads();
        #pragma unroll
        for (int kc = 0; kc < 2; ++kc) {
            s16x8 af[4], bf[4];
            #pragma unroll
            for (int mi = 0; mi < 4; ++mi)
                af[mi] = *(const s16x8*)&As[(wm * 64 + 16 * mi + lrow) * 72 + kc * 32 + quad * 8];
            #pragma unroll
            for (int ni = 0; ni < 4; ++ni)
                bf[ni] = *(const s16x8*)&Bs[(wn * 64 + 16 * ni + lrow) * 72 + kc * 32 + quad * 8];
            #pragma unroll
            for (int mi = 0; mi < 4; ++mi)
                #pragma unroll
                for (int ni = 0; ni < 4; ++ni)
                    acc[mi][ni] = MFMA32(af[mi], bf[ni], acc[mi][ni]);
        }
    }

    const int seg = col0 % 384, typ = seg >> 7, h = col0 / 384;
    const size_t bh = (size_t)bb * NH + h;
    const int sl_blk = row0 & 1023;
    float bia[4];
    #pragma unroll
    for (int ni = 0; ni < 4; ++ni) bia[ni] = bias[col0 + wn * 64 + 16 * ni + lrow];
    const float sc = (typ == 0) ? SCALE : 1.f;

    __syncthreads();
    if (typ < 2) {
        #pragma unroll
        for (int mi = 0; mi < 4; ++mi)
            #pragma unroll
            for (int ni = 0; ni < 4; ++ni)
                #pragma unroll
                for (int reg = 0; reg < 4; ++reg)
                    Rs[(wm * 64 + 16 * mi + quad * 4 + reg) * 136 + wn * 64 + 16 * ni + lrow]
                        = f2bf((acc[mi][ni][reg] + bia[ni]) * sc);
    } else {
        #pragma unroll
        for (int mi = 0; mi < 4; ++mi)
            #pragma unroll
            for (int ni = 0; ni < 4; ++ni) {
                ushort4 pk;
                pk.x = f2bf(acc[mi][ni][0] + bia[ni]);
                pk.y = f2bf(acc[mi][ni][1] + bia[ni]);
                pk.z = f2bf(acc[mi][ni][2] + bia[ni]);
                pk.w = f2bf(acc[mi][ni][3] + bia[ni]);
                *(ushort4*)&Rs[(wn * 64 + 16 * ni + lrow) * 136 + wm * 64 + 16 * mi + quad * 4] = pk;
            }
    }
    __syncthreads();

    ushort* dstb;
    int pitch;
    if (typ == 0)      { dstb = qo  + bh * SS * 128 + (size_t)sl_blk * 128; pitch = 128; }
    else if (typ == 1) { dstb = ko  + bh * SS * 128 + (size_t)sl_blk * 128; pitch = 128; }
    else               { dstb = vto + bh * (size_t)128 * SS + sl_blk;       pitch = SS;  }
    #pragma unroll
    for (int p = 0; p < 8; ++p) {
        int slot = p * 256 + tid;
        int r = slot >> 4, c8 = (slot & 15) * 8;
        *(s16x8*)&dstb[(size_t)r * pitch + c8] = *(const s16x8*)&Rs[r * 136 + c8];
    }
}

// ---------------- K2: round-0 proven MFMA flash attention (verbatim): S^T softmax;
//                  reg-P MFMA16 PV; fused out-proj via LDS epilogue ----------------
static constexpr int KS_LD = 136;
static constexpr int VT_LD = 72;
static constexpr int WS_LD = 136;
static constexpr int OS_LD = 136;
static constexpr int SMEM_N = 26112;   // 52224 B (main: Ks 64*136 + Vt 128*72; epi: Osl 4*16*136 + Ws 128*136)

__global__ __launch_bounds__(256, 2) void attn_fused_kernel(const ushort* __restrict__ qg_,
                                                            const ushort* __restrict__ kg_,
                                                            const ushort* __restrict__ vg_,
                                                            const unsigned long long* __restrict__ mbit,
                                                            const float* __restrict__ wo,
                                                            const float* __restrict__ bo,
                                                            float* __restrict__ out) {
    // XCD swizzle: blockIdx.x = (b,h) so all 8 q-tiles of a (b,h) share id%8 -> same XCD L2
    const int bhi = blockIdx.x, qt = blockIdx.y;
    const int b = bhi >> 2, h = bhi & 3;
    const int s0 = qt * 128;
    const int tid = threadIdx.x;
    const int wave = tid >> 6, lane = tid & 63;
    const int lrow = lane & 15, quad = lane >> 4;

    __shared__ ushort smem[SMEM_N];
    ushort* Ks  = smem;                          // [key][d]
    ushort* Vt  = smem + 64 * KS_LD;             // [d][key]
    ushort* Osl = smem + wave * 16 * OS_LD;      // epilogue: per-wave [q][d], aliases Ks
    ushort* Ws  = smem + 4 * 16 * OS_LD;         // epilogue: Wo[h] bf16 [e][d]

    const size_t bh = (size_t)(b * NH + h);
    const ushort* qg = qg_ + bh * SS * 128;
    const ushort* kg = kg_ + bh * SS * 128;
    const ushort* vg = vg_ + bh * 128 * SS;
    const unsigned long long* mrow0 = mbit + ((size_t)h * SS + (s0 + 32 * wave + lrow)) * 16;
    const unsigned long long* mrow1 = mrow0 + 16 * 16;

    // Q fragments (B-operand of S^T MFMA32): n=q=lane&15, k=kc*32+quad*8+j
    s16x8 qf[2][4];
    #pragma unroll
    for (int g = 0; g < 2; ++g) {
        const ushort* qr = qg + (size_t)(s0 + 32 * wave + 16 * g + lrow) * 128 + quad * 8;
        #pragma unroll
        for (int kc = 0; kc < 4; ++kc) qf[g][kc] = *(const s16x8*)(qr + kc * 32);
    }

    // staging prefetch registers (tile kt=0)
    s16x8 kreg[4], vreg[4];
    #pragma unroll
    for (int p = 0; p < 4; ++p) {
        int slot = p * 256 + tid;
        int r = slot >> 4, c = (slot & 15) * 8;
        kreg[p] = *(const s16x8*)(kg + (size_t)r * 128 + c);
    }
    #pragma unroll
    for (int p = 0; p < 4; ++p) {
        int slot = p * 256 + tid;
        int r = slot >> 3, c = (slot & 7) * 8;
        vreg[p] = *(const s16x8*)(vg + (size_t)r * SS + c);
    }

    // O^T accumulators: D[m=d][n=q]: q = lane&15 (aligned with softmax state!), d = 16*nb+quad*4+reg
    f32x4 oacc[2][8];
    #pragma unroll
    for (int g = 0; g < 2; ++g)
        #pragma unroll
        for (int nb = 0; nb < 8; ++nb) oacc[g][nb] = (f32x4){0.f, 0.f, 0.f, 0.f};
    float m_run[2] = {-INFINITY, -INFINITY};
    float l_run[2] = {0.f, 0.f};

    for (int kt = 0; kt < 16; ++kt) {
        const int t0 = kt * 64;
        unsigned long long mw0 = mrow0[kt];
        unsigned long long mw1 = mrow1[kt];

        __syncthreads();
        #pragma unroll
        for (int p = 0; p < 4; ++p) {
            int slot = p * 256 + tid;
            int r = slot >> 4, c = (slot & 15) * 8;
            *(s16x8*)&Ks[r * KS_LD + c] = kreg[p];
        }
        #pragma unroll
        for (int p = 0; p < 4; ++p) {
            int slot = p * 256 + tid;
            int r = slot >> 3, c = (slot & 7) * 8;
            *(s16x8*)&Vt[r * VT_LD + c] = vreg[p];
        }
        __syncthreads();

        if (kt < 15) {
            const int t1 = t0 + 64;
            #pragma unroll
            for (int p = 0; p < 4; ++p) {
                int slot = p * 256 + tid;
                int r = slot >> 4, c = (slot & 15) * 8;
                kreg[p] = *(const s16x8*)(kg + (size_t)(t1 + r) * 128 + c);
            }
            #pragma unroll
            for (int p = 0; p < 4; ++p) {
                int slot = p * 256 + tid;
                int r = slot >> 3, c = (slot & 7) * 8;
                vreg[p] = *(const s16x8*)(vg + (size_t)r * SS + t1 + c);
            }
        }

        // ---- S^T = K (q/sqrtD)^T : D[m=key][n=q]; key = 16*cb+quad*4+reg, q = lane&15 ----
        f32x4 sacc[2][4];
        #pragma unroll
        for (int g = 0; g < 2; ++g)
            #pragma unroll
            for (int cb = 0; cb < 4; ++cb) sacc[g][cb] = (f32x4){0.f, 0.f, 0.f, 0.f};
        #pragma unroll
        for (int cb = 0; cb < 4; ++cb) {
            s16x8 kf[4];
            #pragma unroll
            for (int kc = 0; kc < 4; ++kc)
                kf[kc] = *(const s16x8*)&Ks[(16 * cb + lrow) * KS_LD + kc * 32 + quad * 8];
            #pragma unroll
            for (int g = 0; g < 2; ++g)
                #pragma unroll
                for (int kc = 0; kc < 4; ++kc)
                    sacc[g][cb] = MFMA32(kf[kc], qf[g][kc], sacc[g][cb]);
        }

        // ---- softmax (per-lane state, q=lane&15) + pf pack (sacc layout == MFMA16 B-operand!) ----
        s16x4 pf[2][4];
        #pragma unroll
        for (int g = 0; g < 2; ++g) {
            const unsigned long long mw = g ? mw1 : mw0;
            float sv[4][4];
            float tm = -INFINITY;
            #pragma unroll
            for (int cb = 0; cb < 4; ++cb) {
                unsigned nib = (unsigned)(mw >> (16 * cb + quad * 4)) & 0xFu;
                #pragma unroll
                for (int r = 0; r < 4; ++r) {
                    sv[cb][r] = (nib & (1u << r)) ? sacc[g][cb][r] : NEGF;
                    tm = fmaxf(tm, sv[cb][r]);
                }
            }
            tm = fmaxf(tm, __shfl_xor(tm, 16));
            tm = fmaxf(tm, __shfl_xor(tm, 32));
            float mn = fmaxf(m_run[g], tm);
            float al = __expf(m_run[g] - mn);
            float rs = 0.f;
            #pragma unroll
            for (int cb = 0; cb < 4; ++cb) {
                float p0 = __expf(sv[cb][0] - mn);
                float p1 = __expf(sv[cb][1] - mn);
                float p2 = __expf(sv[cb][2] - mn);
                float p3 = __expf(sv[cb][3] - mn);
                rs += (p0 + p1) + (p2 + p3);
                s16x4 pk;
                pk[0] = (short)f2bf(p0); pk[1] = (short)f2bf(p1);
                pk[2] = (short)f2bf(p2); pk[3] = (short)f2bf(p3);
                pf[g][cb] = pk;
            }
            rs += __shfl_xor(rs, 16);
            rs += __shfl_xor(rs, 32);
            l_run[g] = l_run[g] * al + rs;
            m_run[g] = mn;
            // O^T rescale: q = lane&15 -> per-lane al applies directly, no transpose
            #pragma unroll
            for (int nb = 0; nb < 8; ++nb)
                #pragma unroll
                for (int r = 0; r < 4; ++r) oacc[g][nb][r] *= al;
        }

        // ---- O^T += V^T P^T : MFMA16, A = V^T frag (b64 LDS), B = pf (registers) ----
        #pragma unroll
        for (int nb = 0; nb < 8; ++nb) {
            #pragma unroll
            for (int kb = 0; kb < 4; ++kb) {
                s16x4 vf = *(const s16x4*)&Vt[(16 * nb + lrow) * VT_LD + kb * 16 + quad * 4];
                #pragma unroll
                for (int g = 0; g < 2; ++g)
                    oacc[g][nb] = MFMA16(vf, pf[g][kb], oacc[g][nb]);
            }
        }
    }

    // ---- fused out-projection: out = (O/l) Wo^T + bo ----
    __syncthreads();
    const float* wbase = wo + (size_t)h * Dh * Dh;
    #pragma unroll
    for (int p = 0; p < 16; ++p) {
        int slot = p * 256 + tid;
        int r = slot >> 5, c4 = (slot & 31) << 2;
        float4 wv = *(const float4*)(wbase + (size_t)r * Dh + c4);
        ushort4 pb;
        pb.x = f2bf(wv.x); pb.y = f2bf(wv.y); pb.z = f2bf(wv.z); pb.w = f2bf(wv.w);
        *(ushort4*)&Ws[r * WS_LD + c4] = pb;
    }
    // per-wave: normalized O^T -> Osl[q][d] (b64 writes, q=lrow rows), reread as A-frags [m=q][k=d]
    s16x8 afo[2][4];
    #pragma unroll
    for (int g = 0; g < 2; ++g) {
        float inv = 1.0f / l_run[g];   // per-lane, q = lane&15: no shuffle needed
        #pragma unroll
        for (int nb = 0; nb < 8; ++nb) {
            ushort4 pk;
            pk.x = f2bf(oacc[g][nb][0] * inv);
            pk.y = f2bf(oacc[g][nb][1] * inv);
            pk.z = f2bf(oacc[g][nb][2] * inv);
            pk.w = f2bf(oacc[g][nb][3] * inv);
            *(ushort4*)&Osl[lrow * OS_LD + 16 * nb + quad * 4] = pk;
        }
        #pragma unroll
        for (int kc = 0; kc < 4; ++kc)
            afo[g][kc] = *(const s16x8*)&Osl[lrow * OS_LD + kc * 32 + quad * 8];
    }
    __syncthreads();

    const size_t orow0 = (size_t)b * SS + s0 + 32 * wave;
    #pragma unroll
    for (int nb = 0; nb < 8; ++nb) {
        float bia = bo[h * Dh + nb * 16 + lrow];
        f32x4 facc[2];
        facc[0] = (f32x4){0.f, 0.f, 0.f, 0.f};
        facc[1] = (f32x4){0.f, 0.f, 0.f, 0.f};
        #pragma unroll
        for (int kc = 0; kc < 4; ++kc) {
            s16x8 wf = *(const s16x8*)&Ws[(16 * nb + lrow) * WS_LD + kc * 32 + quad * 8];
            facc[0] = MFMA32(afo[0][kc], wf, facc[0]);
            facc[1] = MFMA32(afo[1][kc], wf, facc[1]);
        }
        #pragma unroll
        for (int g = 0; g < 2; ++g)
            #pragma unroll
            for (int reg = 0; reg < 4; ++reg) {
                size_t m = orow0 + 16 * g + quad * 4 + reg;
                out[m * (NH * Dh) + h * Dh + nb * 16 + lrow] = facc[g][reg] + bia;
            }
    }
}

extern "C" void kernel_launch(void* const* d_in, const int* in_sizes, int n_in,
                              void* d_out, int out_size, void* d_ws, size_t ws_size,
                              hipStream_t stream) {
    const float* x     = (const float*)d_in[0];
    const int*   edge  = (const int*)d_in[1];
    const float* w_in  = (const float*)d_in[2];
    const float* b_in  = (const float*)d_in[3];
    const float* w_out = (const float*)d_in[4];
    const float* b_out = (const float*)d_in[5];
    float* out = (float*)d_out;

    float* ws   = (float*)d_ws;
    float* part = ws;                                              // 512 floats (reserve 1024)
    unsigned long long* mbit = (unsigned long long*)(ws + 1024);   // [4][1024][16] u64 = 512 KB
    ushort* qo  = (ushort*)(mbit + (size_t)NH * SS * 16);
    const size_t QSZ = (size_t)NB * NH * SS * 128;
    ushort* ko  = qo + QSZ;
    ushort* vto = ko + QSZ;                                        // [b][h][128][s]
    ushort* xb  = vto + QSZ;                                       // [16384][128] bf16 LN'd x (4 MB)
    ushort* wb  = xb + (size_t)NB * SS * Dh;                       // [1536][128] bf16 W_in

    ln_mask_kernel<<<256, 256, 0, stream>>>(x, part, edge, mbit, w_in, wb);
    xcast_kernel<<<1024, 256, 0, stream>>>(x, part, xb);
    qkv_mfma_kernel<<<dim3(12, 128), 256, 0, stream>>>(xb, wb, b_in, qo, ko, vto);
    attn_fused_kernel<<<dim3(NB * NH, SS / 128), 256, 0, stream>>>(qo, ko, vto, mbit, w_out, b_out, out);
}